// Round 11
// baseline (307.417 us; speedup 1.0000x reference)
//
#include <hip/hip_runtime.h>
#include <hip/hip_cooperative_groups.h>
#include <math.h>

namespace cg = cooperative_groups;

// FaceKernelCorrelation: B=8, N=16384, K=64, 4 kernel pts per k, sigma=0.2
// R11 (resubmit of R10 — bench died with UnresponsiveContainer, no data):
// cooperative single-kernel with co-residency margin.
//   R9 failed silently: 2048 blocks need exactly 8 blk/CU (VGPR<=64, zero
//   margin) and the launch error was ignored. Now: 1024 blocks, 2 faces per
//   thread, __launch_bounds__(256,4) (VGPR cap 128, live set ~100), and the
//   launch return code is checked with fallback to the proven R8 3-kernel
//   path (identical output either way).
//   phase 1: gather + kc[2][16] in registers, shuffle-reduce partials -> ws
//   sync -> phase 2: blocks 0..63: reduce 1024 partials -> scale/shift
//   sync -> phase 3: BN+ReLU on register kc, single 33.5MB write.
// Micro: C*|w|^2 folded into fa (|w|=1 to 1ulp; error ~1e-5 << 0.37 thr),
// so each term is 3 FMA + exp2 + acc.

#define NFACES 16384
#define BATCH  8
#define KK     64
#define CNBLK  1024            // cooperative grid: 4 blocks/CU x 256 CU
#define FNBLK  2048            // fallback kc grid

// C = -1/(2*sigma^2) * log2(e)  with sigma = 0.2
__device__ __constant__ const float C_SCALE = -18.033688011112043f;

// ---------------- cooperative fused kernel ----------------
__global__ __launch_bounds__(256, 4) void fused_coop(
    const float* __restrict__ normals,   // [B,3,N]
    const int*   __restrict__ nbr,       // [B,N,3]
    const float* __restrict__ walpha,    // [K*4]
    const float* __restrict__ wbeta,     // [K*4]
    const float* __restrict__ gamma,     // [K]
    const float* __restrict__ beta,      // [K]
    float*       __restrict__ out,       // [B,K,N]
    float*       __restrict__ psum,      // [K][CNBLK]
    float*       __restrict__ psumsq)    // [K][CNBLK]
{
    cg::grid_group grid = cg::this_grid();

    __shared__ float4 sW[KK * 4];        // (m2*wx, m2*wy, m2*wz, --)
    __shared__ float  sScale[KK], sShift[KK];
    __shared__ float  sS[4], sQ[4];

    const int tid = threadIdx.x;
    const int bid = blockIdx.x;

    {
        float a = walpha[tid];
        float b = wbeta[tid];
        float sa = sinf(a), ca = cosf(a);
        float sb = sinf(b), cb = cosf(b);
        const float m2 = -2.0f * C_SCALE;
        sW[tid] = make_float4(m2 * sa * cb, m2 * sa * sb, m2 * ca, 0.0f);
    }
    __syncthreads();

    const int b    = bid >> 7;                        // 128 blocks per batch
    const int lane = tid & 63;
    const int n0   = ((bid & 127) << 7) + lane;       // face A
    const int kq   = tid >> 6;                        // wave id: k-quarter

    // ---- phase 1: gather + kc compute, 2 faces per thread ----
    const float* nb_ = normals + (size_t)b * 3 * NFACES;
    float fx[2][4], fy[2][4], fz[2][4], fa[2][4];
#pragma unroll
    for (int p = 0; p < 2; ++p) {
        const int n = n0 + p * 64;
        fx[p][0] = nb_[n];
        fy[p][0] = nb_[NFACES + n];
        fz[p][0] = nb_[2 * NFACES + n];
        const int* ip = nbr + ((size_t)b * NFACES + n) * 3;
#pragma unroll
        for (int j = 0; j < 3; ++j) {
            int idx = ip[j];
            fx[p][j + 1] = nb_[idx];
            fy[p][j + 1] = nb_[NFACES + idx];
            fz[p][j + 1] = nb_[2 * NFACES + idx];
        }
#pragma unroll
        for (int i = 0; i < 4; ++i)   // C*(|f|^2 + |w|^2), |w|^2 == 1
            fa[p][i] = __builtin_fmaf(C_SCALE,
                fx[p][i] * fx[p][i] + fy[p][i] * fy[p][i] + fz[p][i] * fz[p][i],
                C_SCALE);
    }

    const float4* wp = &sW[kq * 64];
    float kc[2][16];

#pragma unroll
    for (int kk = 0; kk < 16; ++kk) {
        float4 w0 = wp[kk * 4 + 0];
        float4 w1 = wp[kk * 4 + 1];
        float4 w2 = wp[kk * 4 + 2];
        float4 w3 = wp[kk * 4 + 3];
#pragma unroll
        for (int p = 0; p < 2; ++p) {
            float s0 = 0.0f, s1 = 0.0f, s2 = 0.0f, s3 = 0.0f;
#pragma unroll
            for (int i = 0; i < 4; ++i) {
                float t0 = __builtin_fmaf(w0.x, fx[p][i],
                            __builtin_fmaf(w0.y, fy[p][i],
                             __builtin_fmaf(w0.z, fz[p][i], fa[p][i])));
                float t1 = __builtin_fmaf(w1.x, fx[p][i],
                            __builtin_fmaf(w1.y, fy[p][i],
                             __builtin_fmaf(w1.z, fz[p][i], fa[p][i])));
                float t2 = __builtin_fmaf(w2.x, fx[p][i],
                            __builtin_fmaf(w2.y, fy[p][i],
                             __builtin_fmaf(w2.z, fz[p][i], fa[p][i])));
                float t3 = __builtin_fmaf(w3.x, fx[p][i],
                            __builtin_fmaf(w3.y, fy[p][i],
                             __builtin_fmaf(w3.z, fz[p][i], fa[p][i])));
                s0 += __builtin_amdgcn_exp2f(t0);
                s1 += __builtin_amdgcn_exp2f(t1);
                s2 += __builtin_amdgcn_exp2f(t2);
                s3 += __builtin_amdgcn_exp2f(t3);
            }
            kc[p][kk] = ((s0 + s1) + (s2 + s3)) * 0.0625f;
        }
    }

    // Per-k partials over this wave's 128 faces.
    {
        const int kbase = kq * 16;
#pragma unroll
        for (int kk = 0; kk < 16; ++kk) {
            float v = kc[0][kk] + kc[1][kk];
            float q = __builtin_fmaf(kc[0][kk], kc[0][kk],
                                     kc[1][kk] * kc[1][kk]);
#pragma unroll
            for (int off = 32; off > 0; off >>= 1) {
                v += __shfl_down(v, off, 64);
                q += __shfl_down(q, off, 64);
            }
            if (lane == 0) {
                psum[(size_t)(kbase + kk) * CNBLK + bid]   = v;
                psumsq[(size_t)(kbase + kk) * CNBLK + bid] = q;
            }
        }
    }

    grid.sync();

    // ---- phase 2: blocks 0..63 reduce one k each -> scale/shift ----
    if (bid < KK) {
        const int k = bid;
        const float4* ps = reinterpret_cast<const float4*>(psum   + (size_t)k * CNBLK);
        const float4* pq = reinterpret_cast<const float4*>(psumsq + (size_t)k * CNBLK);
        float4 a0 = ps[tid];
        float4 c0 = pq[tid];
        float s = (a0.x + a0.y) + (a0.z + a0.w);
        float q = (c0.x + c0.y) + (c0.z + c0.w);
#pragma unroll
        for (int off = 32; off > 0; off >>= 1) {
            s += __shfl_down(s, off, 64);
            q += __shfl_down(q, off, 64);
        }
        const int l = tid & 63, wid = tid >> 6;
        if (l == 0) { sS[wid] = s; sQ[wid] = q; }
        __syncthreads();
        if (tid == 0) {
            float sum = (sS[0] + sS[1]) + (sS[2] + sS[3]);
            float sq  = (sQ[0] + sQ[1]) + (sQ[2] + sQ[3]);
            const float invN = 1.0f / (float)(BATCH * NFACES);
            float mean = sum * invN;
            float var  = sq * invN - mean * mean;
            float sc = gamma[k] / sqrtf(var + 1e-5f);
            psum[(size_t)k * CNBLK]   = sc;                    // scale[k]
            psumsq[(size_t)k * CNBLK] = beta[k] - mean * sc;   // shift[k]
        }
    }

    grid.sync();

    // ---- phase 3: BN + ReLU on register kc, single write ----
    if (tid < KK)            sScale[tid]      = psum[(size_t)tid * CNBLK];
    else if (tid < 2 * KK)   sShift[tid - KK] = psumsq[(size_t)(tid - KK) * CNBLK];
    __syncthreads();

    float* outp = out + ((size_t)b * KK + kq * 16) * NFACES + n0;
    const int kbase = kq * 16;
#pragma unroll
    for (int kk = 0; kk < 16; ++kk) {
        float sc = sScale[kbase + kk];
        float sh = sShift[kbase + kk];
        float* o = outp + (size_t)kk * NFACES;
        o[0]  = fmaxf(__builtin_fmaf(kc[0][kk], sc, sh), 0.0f);
        o[64] = fmaxf(__builtin_fmaf(kc[1][kk], sc, sh), 0.0f);
    }
}

// ---------------- fallback path (R8, proven 53.3us) ----------------
__global__ __launch_bounds__(256, 4) void kc_kernel(
    const float* __restrict__ normals,
    const int*   __restrict__ nbr,
    const float* __restrict__ walpha,
    const float* __restrict__ wbeta,
    float*       __restrict__ out,
    float*       __restrict__ psum,      // [K][FNBLK]
    float*       __restrict__ psumsq)
{
    __shared__ float4 sW[KK * 4];
    __shared__ float  sT[4][64][17];

    const int tid = threadIdx.x;
    {
        float a = walpha[tid];
        float b = wbeta[tid];
        float sa = sinf(a), ca = cosf(a);
        float sb = sinf(b), cb = cosf(b);
        const float m2 = -2.0f * C_SCALE;
        sW[tid] = make_float4(m2 * sa * cb, m2 * sa * sb, m2 * ca, 0.0f);
    }
    __syncthreads();

    const int b    = blockIdx.x >> 8;
    const int lane = tid & 63;
    const int n    = ((blockIdx.x & 255) << 6) + lane;
    const int kq   = tid >> 6;

    const float* nb_ = normals + (size_t)b * 3 * NFACES;
    float fx[4], fy[4], fz[4], fa[4];
    fx[0] = nb_[n];
    fy[0] = nb_[NFACES + n];
    fz[0] = nb_[2 * NFACES + n];
    const int* ip = nbr + ((size_t)b * NFACES + n) * 3;
#pragma unroll
    for (int j = 0; j < 3; ++j) {
        int idx = ip[j];
        fx[j + 1] = nb_[idx];
        fy[j + 1] = nb_[NFACES + idx];
        fz[j + 1] = nb_[2 * NFACES + idx];
    }
#pragma unroll
    for (int i = 0; i < 4; ++i)
        fa[i] = __builtin_fmaf(C_SCALE,
            fx[i] * fx[i] + fy[i] * fy[i] + fz[i] * fz[i], C_SCALE);

    float* outp = out + ((size_t)b * KK + kq * 16) * NFACES + n;
    const float4* wp = &sW[kq * 64];

#pragma unroll
    for (int kk = 0; kk < 16; ++kk) {
        float4 w0 = wp[kk * 4 + 0];
        float4 w1 = wp[kk * 4 + 1];
        float4 w2 = wp[kk * 4 + 2];
        float4 w3 = wp[kk * 4 + 3];
        float s0 = 0.0f, s1 = 0.0f, s2 = 0.0f, s3 = 0.0f;
#pragma unroll
        for (int i = 0; i < 4; ++i) {
            float t0 = __builtin_fmaf(w0.x, fx[i],
                        __builtin_fmaf(w0.y, fy[i],
                         __builtin_fmaf(w0.z, fz[i], fa[i])));
            float t1 = __builtin_fmaf(w1.x, fx[i],
                        __builtin_fmaf(w1.y, fy[i],
                         __builtin_fmaf(w1.z, fz[i], fa[i])));
            float t2 = __builtin_fmaf(w2.x, fx[i],
                        __builtin_fmaf(w2.y, fy[i],
                         __builtin_fmaf(w2.z, fz[i], fa[i])));
            float t3 = __builtin_fmaf(w3.x, fx[i],
                        __builtin_fmaf(w3.y, fy[i],
                         __builtin_fmaf(w3.z, fz[i], fa[i])));
            s0 += __builtin_amdgcn_exp2f(t0);
            s1 += __builtin_amdgcn_exp2f(t1);
            s2 += __builtin_amdgcn_exp2f(t2);
            s3 += __builtin_amdgcn_exp2f(t3);
        }
        float kc = ((s0 + s1) + (s2 + s3)) * 0.0625f;
        outp[(size_t)kk * NFACES] = kc;
        sT[kq][lane][kk] = kc;
    }

    {
        const int kk = lane & 15, seg = lane >> 4;
        float v = 0.0f, q = 0.0f;
#pragma unroll
        for (int j = 0; j < 16; ++j) {
            float x = sT[kq][seg * 16 + j][kk];
            v += x;
            q = __builtin_fmaf(x, x, q);
        }
        v += __shfl_xor(v, 16, 64);  q += __shfl_xor(q, 16, 64);
        v += __shfl_xor(v, 32, 64);  q += __shfl_xor(q, 32, 64);
        if (seg == 0) {
            const int k = kq * 16 + kk;
            psum[(size_t)k * FNBLK + blockIdx.x]   = v;
            psumsq[(size_t)k * FNBLK + blockIdx.x] = q;
        }
    }
}

__global__ __launch_bounds__(256) void fin_kernel(
    const float* __restrict__ psum,
    const float* __restrict__ psumsq,
    const float* __restrict__ gamma,
    const float* __restrict__ beta,
    float*       __restrict__ scale,
    float*       __restrict__ shift)
{
    const int k = blockIdx.x;
    const int tid = threadIdx.x;
    const float4* ps = reinterpret_cast<const float4*>(psum   + (size_t)k * FNBLK);
    const float4* pq = reinterpret_cast<const float4*>(psumsq + (size_t)k * FNBLK);

    float s = 0.0f, q = 0.0f;
#pragma unroll
    for (int i = 0; i < 2; ++i) {
        float4 a = ps[i * 256 + tid];
        float4 c = pq[i * 256 + tid];
        s += (a.x + a.y) + (a.z + a.w);
        q += (c.x + c.y) + (c.z + c.w);
    }

    __shared__ float sS[4], sQ[4];
#pragma unroll
    for (int off = 32; off > 0; off >>= 1) {
        s += __shfl_down(s, off, 64);
        q += __shfl_down(q, off, 64);
    }
    const int lane = tid & 63, wid = tid >> 6;
    if (lane == 0) { sS[wid] = s; sQ[wid] = q; }
    __syncthreads();
    if (tid == 0) {
        float sum = (sS[0] + sS[1]) + (sS[2] + sS[3]);
        float sq  = (sQ[0] + sQ[1]) + (sQ[2] + sQ[3]);
        const float invN = 1.0f / (float)(BATCH * NFACES);
        float mean = sum * invN;
        float var  = sq * invN - mean * mean;
        float sc = gamma[k] / sqrtf(var + 1e-5f);
        scale[k] = sc;
        shift[k] = beta[k] - mean * sc;
    }
}

__global__ __launch_bounds__(256) void bn_kernel(
    float* __restrict__ out,
    const float* __restrict__ scale,
    const float* __restrict__ shift)
{
    const size_t idx = (size_t)blockIdx.x * 256 + threadIdx.x;
    const int k = (int)((idx >> 12) & 63);
    float4 v = reinterpret_cast<float4*>(out)[idx];
    const float sc = scale[k], sh = shift[k];
    v.x = fmaxf(__builtin_fmaf(v.x, sc, sh), 0.0f);
    v.y = fmaxf(__builtin_fmaf(v.y, sc, sh), 0.0f);
    v.z = fmaxf(__builtin_fmaf(v.z, sc, sh), 0.0f);
    v.w = fmaxf(__builtin_fmaf(v.w, sc, sh), 0.0f);
    reinterpret_cast<float4*>(out)[idx] = v;
}

extern "C" void kernel_launch(void* const* d_in, const int* in_sizes, int n_in,
                              void* d_out, int out_size, void* d_ws, size_t ws_size,
                              hipStream_t stream) {
    const float* normals = (const float*)d_in[0];
    const int*   nbr     = (const int*)d_in[1];
    const float* walpha  = (const float*)d_in[2];
    const float* wbeta   = (const float*)d_in[3];
    const float* gamma   = (const float*)d_in[4];
    const float* beta    = (const float*)d_in[5];
    float* out = (float*)d_out;

    // ws layout sized for the larger (fallback) configuration.
    float* psum   = (float*)d_ws;               // [64][2048] (coop uses [64][1024])
    float* psumsq = psum + KK * FNBLK;
    float* scale  = psumsq + KK * FNBLK;        // fallback only
    float* shift  = scale + KK;

    void* args[] = {
        (void*)&normals, (void*)&nbr, (void*)&walpha, (void*)&wbeta,
        (void*)&gamma, (void*)&beta, (void*)&out, (void*)&psum, (void*)&psumsq
    };
    hipError_t rc = hipLaunchCooperativeKernel((const void*)fused_coop,
                                               dim3(CNBLK), dim3(256), args, 0, stream);
    if (rc != hipSuccess) {
        (void)hipGetLastError();   // clear sticky error, run proven 3-kernel path
        kc_kernel<<<FNBLK, 256, 0, stream>>>(normals, nbr, walpha, wbeta, out, psum, psumsq);
        fin_kernel<<<KK, 256, 0, stream>>>(psum, psumsq, gamma, beta, scale, shift);
        const int total_f4 = (BATCH * KK * NFACES) / 4;
        bn_kernel<<<total_f4 / 256, 256, 0, stream>>>(out, scale, shift);
    }
}

// Round 12
// 48.094 us; speedup vs baseline: 6.3921x; 6.3921x over previous
//
#include <hip/hip_runtime.h>
#include <math.h>

// FaceKernelCorrelation: B=8, N=16384, K=64, 4 kernel pts per k, sigma=0.2
// R12: back to the proven R8 3-kernel skeleton (coop fusion abandoned: R11
// showed the allocator targets 8 waves/EU, gave 64 VGPR, spilled ~100-reg
// live set -> 293us scratch-bound). kc inner loop re-done for PACKED f32:
//   - fea points processed as float2 pairs via __builtin_elementwise_fma
//     -> v_pk_fma_f32 (gfx950 packed-f32 2x rate; the 157 TF spec rate)
//   - |w|^2 == 1 fold + fa folded as FMA-chain init (no per-term add)
// Pipeline:
//  1) kc_kernel:  gather fea, kc[b,k,n] -> out + fused per-block stats
//     partials via conflict-free LDS transpose ([4][64][17]).
//  2) fin_kernel: 64 blocks: reduce 2048 partials -> scale/shift.
//  3) bn_kernel:  in-place float4 y = relu(kc*scale + shift).

#define NFACES 16384
#define BATCH  8
#define KK     64
#define NBLK   2048            // kc grid: BATCH * (NFACES/64)

typedef float v2f __attribute__((ext_vector_type(2)));

// C = -1/(2*sigma^2) * log2(e)  with sigma = 0.2
__device__ __constant__ const float C_SCALE = -18.033688011112043f;

__global__ __launch_bounds__(256, 7) void kc_kernel(
    const float* __restrict__ normals,   // [B,3,N]
    const int*   __restrict__ nbr,       // [B,N,3]
    const float* __restrict__ walpha,    // [K*4]
    const float* __restrict__ wbeta,     // [K*4]
    float*       __restrict__ out,       // [B,K,N]
    float*       __restrict__ psum,      // [K][NBLK]
    float*       __restrict__ psumsq)    // [K][NBLK]
{
    __shared__ float4 sW[KK * 4];        // (m2*wx, m2*wy, m2*wz, 0)
    __shared__ float  sT[4][64][17];     // [wave][lane][k] transpose tile

    const int tid = threadIdx.x;

    // Kernel-point table: 256 threads -> 256 (k,j) entries
    {
        float a = walpha[tid];
        float b = wbeta[tid];
        float sa = sinf(a), ca = cosf(a);
        float sb = sinf(b), cb = cosf(b);
        const float m2 = -2.0f * C_SCALE;
        sW[tid] = make_float4(m2 * sa * cb, m2 * sa * sb, m2 * ca, 0.0f);
    }
    __syncthreads();

    const int b    = blockIdx.x >> 8;
    const int lane = tid & 63;
    const int n    = ((blockIdx.x & 255) << 6) + lane;
    const int kq   = tid >> 6;

    const float* nb_ = normals + (size_t)b * 3 * NFACES;
    float fx[4], fy[4], fz[4];
    fx[0] = nb_[n];
    fy[0] = nb_[NFACES + n];
    fz[0] = nb_[2 * NFACES + n];
    const int* ip = nbr + ((size_t)b * NFACES + n) * 3;
#pragma unroll
    for (int j = 0; j < 3; ++j) {
        int idx = ip[j];
        fx[j + 1] = nb_[idx];
        fy[j + 1] = nb_[NFACES + idx];
        fz[j + 1] = nb_[2 * NFACES + idx];
    }

    // Pack the 4 fea points into float2 pairs for v_pk_fma_f32.
    v2f fx01 = {fx[0], fx[1]}, fx23 = {fx[2], fx[3]};
    v2f fy01 = {fy[0], fy[1]}, fy23 = {fy[2], fy[3]};
    v2f fz01 = {fz[0], fz[1]}, fz23 = {fz[2], fz[3]};
    // fa_i = C*(|f_i|^2 + |w|^2), |w|^2 == 1 (to 1ulp)  — chain init term
    v2f fa01, fa23;
    {
        v2f n01 = fx01 * fx01 + fy01 * fy01 + fz01 * fz01;
        v2f n23 = fx23 * fx23 + fy23 * fy23 + fz23 * fz23;
        fa01 = (v2f){C_SCALE, C_SCALE} * n01 + (v2f){C_SCALE, C_SCALE};
        fa23 = (v2f){C_SCALE, C_SCALE} * n23 + (v2f){C_SCALE, C_SCALE};
    }

    float* outp = out + ((size_t)b * KK + kq * 16) * NFACES + n;
    const float4* wp = &sW[kq * 64];

#pragma unroll
    for (int kk = 0; kk < 16; ++kk) {
        float s0 = 0.0f, s1 = 0.0f, s2 = 0.0f, s3 = 0.0f;
#pragma unroll
        for (int j = 0; j < 4; ++j) {
            float4 w = wp[kk * 4 + j];
            v2f wx = {w.x, w.x}, wy = {w.y, w.y}, wz = {w.z, w.z};
            v2f t01 = __builtin_elementwise_fma(wx, fx01,
                        __builtin_elementwise_fma(wy, fy01,
                          __builtin_elementwise_fma(wz, fz01, fa01)));
            v2f t23 = __builtin_elementwise_fma(wx, fx23,
                        __builtin_elementwise_fma(wy, fy23,
                          __builtin_elementwise_fma(wz, fz23, fa23)));
            s0 += __builtin_amdgcn_exp2f(t01.x);
            s1 += __builtin_amdgcn_exp2f(t01.y);
            s2 += __builtin_amdgcn_exp2f(t23.x);
            s3 += __builtin_amdgcn_exp2f(t23.y);
        }
        float kc = ((s0 + s1) + (s2 + s3)) * 0.0625f;
        outp[(size_t)kk * NFACES] = kc;
        sT[kq][lane][kk] = kc;               // intra-wave: no barrier needed
    }

    // Per-wave transpose reduce (reads exactly 2-way -> free).
    {
        const int kk = lane & 15, seg = lane >> 4;
        float v = 0.0f, q = 0.0f;
#pragma unroll
        for (int j = 0; j < 16; ++j) {
            float x = sT[kq][seg * 16 + j][kk];
            v += x;
            q = __builtin_fmaf(x, x, q);
        }
        v += __shfl_xor(v, 16, 64);  q += __shfl_xor(q, 16, 64);
        v += __shfl_xor(v, 32, 64);  q += __shfl_xor(q, 32, 64);
        if (seg == 0) {
            const int k = kq * 16 + kk;
            psum[(size_t)k * NBLK + blockIdx.x]   = v;
            psumsq[(size_t)k * NBLK + blockIdx.x] = q;
        }
    }
}

// One block per k: reduce 2048 partials -> scale/shift.
__global__ __launch_bounds__(256) void fin_kernel(
    const float* __restrict__ psum,
    const float* __restrict__ psumsq,
    const float* __restrict__ gamma,
    const float* __restrict__ beta,
    float*       __restrict__ scale,
    float*       __restrict__ shift)
{
    const int k = blockIdx.x;
    const int tid = threadIdx.x;
    const float4* ps = reinterpret_cast<const float4*>(psum   + (size_t)k * NBLK);
    const float4* pq = reinterpret_cast<const float4*>(psumsq + (size_t)k * NBLK);

    float s = 0.0f, q = 0.0f;
#pragma unroll
    for (int i = 0; i < 2; ++i) {
        float4 a = ps[i * 256 + tid];
        float4 c = pq[i * 256 + tid];
        s += (a.x + a.y) + (a.z + a.w);
        q += (c.x + c.y) + (c.z + c.w);
    }

    __shared__ float sS[4], sQ[4];
#pragma unroll
    for (int off = 32; off > 0; off >>= 1) {
        s += __shfl_down(s, off, 64);
        q += __shfl_down(q, off, 64);
    }
    const int lane = tid & 63, wid = tid >> 6;
    if (lane == 0) { sS[wid] = s; sQ[wid] = q; }
    __syncthreads();
    if (tid == 0) {
        float sum = (sS[0] + sS[1]) + (sS[2] + sS[3]);
        float sq  = (sQ[0] + sQ[1]) + (sQ[2] + sQ[3]);
        const float invN = 1.0f / (float)(BATCH * NFACES);
        float mean = sum * invN;
        float var  = sq * invN - mean * mean;
        float sc = gamma[k] / sqrtf(var + 1e-5f);
        scale[k] = sc;
        shift[k] = beta[k] - mean * sc;
    }
}

__global__ __launch_bounds__(256) void bn_kernel(
    float* __restrict__ out,
    const float* __restrict__ scale,
    const float* __restrict__ shift)
{
    const size_t idx = (size_t)blockIdx.x * 256 + threadIdx.x;
    const int k = (int)((idx >> 12) & 63);
    float4 v = reinterpret_cast<float4*>(out)[idx];
    const float sc = scale[k], sh = shift[k];
    v.x = fmaxf(__builtin_fmaf(v.x, sc, sh), 0.0f);
    v.y = fmaxf(__builtin_fmaf(v.y, sc, sh), 0.0f);
    v.z = fmaxf(__builtin_fmaf(v.z, sc, sh), 0.0f);
    v.w = fmaxf(__builtin_fmaf(v.w, sc, sh), 0.0f);
    reinterpret_cast<float4*>(out)[idx] = v;
}

extern "C" void kernel_launch(void* const* d_in, const int* in_sizes, int n_in,
                              void* d_out, int out_size, void* d_ws, size_t ws_size,
                              hipStream_t stream) {
    const float* normals = (const float*)d_in[0];
    const int*   nbr     = (const int*)d_in[1];
    const float* walpha  = (const float*)d_in[2];
    const float* wbeta   = (const float*)d_in[3];
    const float* gamma   = (const float*)d_in[4];
    const float* beta    = (const float*)d_in[5];
    float* out = (float*)d_out;

    float* psum   = (float*)d_ws;              // [64][2048]
    float* psumsq = psum + KK * NBLK;          // [64][2048]
    float* scale  = psumsq + KK * NBLK;        // [64]
    float* shift  = scale + KK;                // [64]

    kc_kernel<<<NBLK, 256, 0, stream>>>(normals, nbr, walpha, wbeta, out, psum, psumsq);
    fin_kernel<<<KK, 256, 0, stream>>>(psum, psumsq, gamma, beta, scale, shift);

    const int total_f4 = (BATCH * KK * NFACES) / 4;   // 2,097,152
    bn_kernel<<<total_f4 / 256, 256, 0, stream>>>(out, scale, shift);
}